// Round 1
// baseline (4311.153 us; speedup 1.0000x reference)
//
#include <hip/hip_runtime.h>
#include <math.h>

// EmergentResonator: recurrent spiking net.
// B=4096 rows, each row independent through T=64 input steps + 16 reasoning steps.
// Persistent blocks: 256 blocks x 16 rows, state (spikes in LDS, potential in VGPRs)
// carried across all 80 steps. W_rec streamed from L2 each step in a transposed,
// k-interleaved layout (one dwordx4 per lane per 4-k chunk).

#define NET   360
#define NETP  384          // padded column count (6 waves * 64 lanes)
#define RPB   16           // rows per block
#define TIN   28           // input feature size
#define NBLK  256          // 256*16 = 4096 rows
#define NTHR  384          // one thread per (padded) column

// Prep: Wt2 layout: for chunk c=k/4, Wt2[(c*NETP + n)*4 + (k&3)] = W_rec[n*NET + k],
// zero for n >= NET. Size = 90*384*4 floats = 553 KB in d_ws.
__global__ void prep_kernel(const float* __restrict__ W_rec, float* __restrict__ Wt)
{
    int idx = blockIdx.x * blockDim.x + threadIdx.x;
    const int total = (NET / 4) * NETP * 4;
    if (idx < total) {
        int c   = idx / (NETP * 4);
        int rem = idx - c * (NETP * 4);
        int n   = rem >> 2;
        int kk  = rem & 3;
        int k   = c * 4 + kk;
        Wt[idx] = (n < NET) ? W_rec[n * NET + k] : 0.0f;
    }
}

__global__ __launch_bounds__(NTHR)
void resonator_kernel(const float* __restrict__ x,
                      const int*   __restrict__ rsteps_p,
                      const float* __restrict__ W_in,
                      const float* __restrict__ b_in,
                      const float* __restrict__ W_gate,
                      const float* __restrict__ b_gate,
                      const float* __restrict__ ln_g,
                      const float* __restrict__ ln_b,
                      const float* __restrict__ thr_p,
                      const float* __restrict__ intr_p,
                      const float* __restrict__ steep_p,
                      const float* __restrict__ reset_p,
                      const float* __restrict__ W_cls,
                      const float* __restrict__ b_cls,
                      const float* __restrict__ Wt,
                      float* __restrict__ out)
{
    __shared__ __align__(16) float spk[RPB][NETP];   // spikes state, 24.6 KB
    __shared__ float red[NTHR / 64][RPB][2];         // per-wave LN partials
    __shared__ float musig[2][RPB];                  // mu / rsigma per row

    const int  tid  = threadIdx.x;
    const int  j    = tid;                 // column index (padded)
    const bool act  = (j < NET);
    const int  lane = tid & 63;
    const int  wv   = tid >> 6;
    const int  row0 = blockIdx.x * RPB;

    // Pin per-column params + W_in/W_gate columns in registers.
    float win[TIN], wgt[TIN];
    float bin = 0.f, bgt = 0.f, gam = 0.f, bet = 0.f;
    float thr = 0.f, intr = 0.f, asteep = 0.f, rsc = 0.f;
    if (act) {
#pragma unroll
        for (int k = 0; k < TIN; ++k) { win[k] = W_in[j * TIN + k]; wgt[k] = W_gate[j * TIN + k]; }
        bin = b_in[j]; bgt = b_gate[j]; gam = ln_g[j]; bet = ln_b[j];
        thr = thr_p[j]; intr = intr_p[j]; asteep = fabsf(steep_p[j]); rsc = reset_p[j];
    } else {
#pragma unroll
        for (int k = 0; k < TIN; ++k) { win[k] = 0.f; wgt[k] = 0.f; }
    }

    float pot[RPB], acc[RPB];
#pragma unroll
    for (int r = 0; r < RPB; ++r) { pot[r] = 0.f; spk[r][j] = 0.f; }

    const int rsteps = *rsteps_p;
    const int Ttot   = 64 + rsteps;

    const float4* wp = ((const float4*)Wt) + j;   // lane's column, chunk stride NETP float4s

    for (int t = 0; t < Ttot; ++t) {
        __syncthreads();   // barrier A: spikes from prev step visible

#pragma unroll
        for (int r = 0; r < RPB; ++r) acc[r] = 0.f;

        // Recurrent GEMV: acc[r] += sum_k spk[r][k] * W_rec[j][k]
#pragma unroll 2
        for (int c = 0; c < NET / 4; ++c) {
            float4 w = wp[(size_t)c * NETP];       // coalesced dwordx4 from L2
            const int k0 = c * 4;
#pragma unroll
            for (int r = 0; r < RPB; ++r) {
                float4 s = *(const float4*)&spk[r][k0];  // LDS broadcast b128
                acc[r] = fmaf(s.x, w.x, acc[r]);
                acc[r] = fmaf(s.y, w.y, acc[r]);
                acc[r] = fmaf(s.z, w.z, acc[r]);
                acc[r] = fmaf(s.w, w.w, acc[r]);
            }
        }

        // Gated input (scan phase only): cur += (x@W_in^T + b_in) * sigmoid(x@W_gate^T + b_gate)
        if (t < 64) {
#pragma unroll
            for (int r = 0; r < RPB; ++r) {
                const float* xr = x + ((size_t)(row0 + r) * 64 + t) * TIN;  // uniform -> s_load
                float ia = bin, ga = bgt;
#pragma unroll
                for (int k = 0; k < TIN; ++k) {
                    float xv = xr[k];
                    ia = fmaf(xv, win[k], ia);
                    ga = fmaf(xv, wgt[k], ga);
                }
                float gate = 1.f / (1.f + __expf(-ga));
                if (act) acc[r] += ia * gate;
            }
        }

        // LayerNorm stats: reduce sum/sumsq over 360 active columns per row
#pragma unroll
        for (int r = 0; r < RPB; ++r) {
            float v  = act ? acc[r] : 0.f;
            float v2 = v * v;
#pragma unroll
            for (int off = 32; off > 0; off >>= 1) {
                v  += __shfl_xor(v,  off, 64);
                v2 += __shfl_xor(v2, off, 64);
            }
            if (lane == 0) { red[wv][r][0] = v; red[wv][r][1] = v2; }
        }
        __syncthreads();   // barrier B (also guarantees all spk reads done)
        if (tid < RPB) {
            float s = 0.f, s2 = 0.f;
#pragma unroll
            for (int w2 = 0; w2 < NTHR / 64; ++w2) { s += red[w2][tid][0]; s2 += red[w2][tid][1]; }
            float mu  = s * (1.f / NET);
            float var = s2 * (1.f / NET) - mu * mu;
            musig[0][tid] = mu;
            musig[1][tid] = rsqrtf(var + 1e-5f);
        }
        __syncthreads();   // barrier C: musig visible

        // LN apply + PulseTGAU neuron step, write new spikes
#pragma unroll
        for (int r = 0; r < RPB; ++r) {
            float cur = (acc[r] - musig[0][r]) * musig[1][r] * gam + bet;
            float p   = pot[r] * 0.95f + cur + intr;
            float gp  = p - thr;
            float sg  = 1.f / (1.f + __expf(-gp * asteep));
            float sgp = 1.f / (1.f + __expf(-gp));
            spk[r][j] = gp * sgp * sg;           // silu(gp) * sg
            pot[r]    = p - rsc * (gp * sg);
        }
    }

    __syncthreads();
    // Classifier epilogue: out[row, c] = spikes . W_cls[c] + b_cls[c]
    if (tid < RPB * 10) {
        int r = tid / 10, cc = tid % 10;
        const float* wc = W_cls + cc * NET;
        float s = b_cls[cc];
        for (int k = 0; k < NET; ++k) s = fmaf(spk[r][k], wc[k], s);
        out[(size_t)(row0 + r) * 10 + cc] = s;
    }
}

extern "C" void kernel_launch(void* const* d_in, const int* in_sizes, int n_in,
                              void* d_out, int out_size, void* d_ws, size_t ws_size,
                              hipStream_t stream)
{
    const float* x      = (const float*)d_in[0];
    const int*   rsteps = (const int*)  d_in[1];
    const float* W_in   = (const float*)d_in[2];
    const float* b_in   = (const float*)d_in[3];
    const float* W_gate = (const float*)d_in[4];
    const float* b_gate = (const float*)d_in[5];
    const float* W_rec  = (const float*)d_in[6];
    const float* ln_g   = (const float*)d_in[7];
    const float* ln_b   = (const float*)d_in[8];
    const float* thr    = (const float*)d_in[9];
    const float* intr   = (const float*)d_in[10];
    const float* steep  = (const float*)d_in[11];
    const float* rsc    = (const float*)d_in[12];
    const float* W_cls  = (const float*)d_in[13];
    const float* b_cls  = (const float*)d_in[14];
    float*       out    = (float*)d_out;
    float*       Wt     = (float*)d_ws;        // 553 KB transposed W_rec

    const int total = (NET / 4) * NETP * 4;
    prep_kernel<<<dim3((total + 255) / 256), dim3(256), 0, stream>>>(W_rec, Wt);
    resonator_kernel<<<dim3(NBLK), dim3(NTHR), 0, stream>>>(
        x, rsteps, W_in, b_in, W_gate, b_gate, ln_g, ln_b,
        thr, intr, steep, rsc, W_cls, b_cls, Wt, out);
}

// Round 2
// 2435.684 us; speedup vs baseline: 1.7700x; 1.7700x over previous
//
#include <hip/hip_runtime.h>
#include <math.h>

// EmergentResonator — MFMA split-f16 version.
// 256 blocks x 16 rows; per step: [16x384]x[384x384] GEMM via mfma_f32_16x16x32_f16,
// 2-way f16 split (hi+lo, 3 products) for ~fp32 accuracy. Spikes kept in LDS in
// A-fragment layout, split to f16 hi/lo each step. Input GEMV (28->360, W_in & W_gate)
// also via MFMA with K padded to 32. Potential state thread-local in the fixed C/D map.

#define NET    360
#define NPAD   384
#define K8N    48          // NPAD/8 k8-groups for W_rec
#define RPB    16
#define NBLK   256
#define NTHR   384         // 6 waves; wave w owns ntiles 4w..4w+3

typedef _Float16 f16x8 __attribute__((ext_vector_type(8)));
typedef float    f32x4 __attribute__((ext_vector_type(4)));

#define WREC_E (K8N * NPAD * 8)    // 147456 f16 per term
#define WIN_E  (4 * NPAD * 8)      // 12288 f16 per term (K pad 32)

// Split fp32 weights into f16 hi/lo in MFMA B-fragment layout:
// idx = (k8*NPAD + n)*8 + (k&7), B[k][n] = W[n*K + k], zero-padded.
__global__ void prep_kernel(const float* __restrict__ W_rec,
                            const float* __restrict__ W_in,
                            const float* __restrict__ W_gate,
                            _Float16* __restrict__ Bh, _Float16* __restrict__ Bl,
                            _Float16* __restrict__ Wih, _Float16* __restrict__ Wil,
                            _Float16* __restrict__ Wgh, _Float16* __restrict__ Wgl)
{
    int idx = blockIdx.x * 256 + threadIdx.x;
    if (idx < WREC_E) {
        int k8 = idx / (NPAD * 8), rem = idx % (NPAD * 8);
        int n = rem >> 3, j = rem & 7, k = k8 * 8 + j;
        float v = (k < NET && n < NET) ? W_rec[n * NET + k] : 0.f;
        _Float16 h = (_Float16)v;
        Bh[idx] = h; Bl[idx] = (_Float16)(v - (float)h);
    } else if (idx < WREC_E + WIN_E) {
        int e = idx - WREC_E;
        int k8 = e / (NPAD * 8), rem = e % (NPAD * 8);
        int n = rem >> 3, j = rem & 7, k = k8 * 8 + j;
        float v = (k < 28 && n < NET) ? W_in[n * 28 + k] : 0.f;
        _Float16 h = (_Float16)v;
        Wih[e] = h; Wil[e] = (_Float16)(v - (float)h);
    } else if (idx < WREC_E + 2 * WIN_E) {
        int e = idx - WREC_E - WIN_E;
        int k8 = e / (NPAD * 8), rem = e % (NPAD * 8);
        int n = rem >> 3, j = rem & 7, k = k8 * 8 + j;
        float v = (k < 28 && n < NET) ? W_gate[n * 28 + k] : 0.f;
        _Float16 h = (_Float16)v;
        Wgh[e] = h; Wgl[e] = (_Float16)(v - (float)h);
    }
}

__device__ __forceinline__ float sigm(float v) { return 1.f / (1.f + __expf(-v)); }

__global__ __launch_bounds__(NTHR, 2)
void resonator_kernel(const float* __restrict__ x,
                      const int*   __restrict__ rsteps_p,
                      const float* __restrict__ b_in,
                      const float* __restrict__ b_gate,
                      const float* __restrict__ ln_g,
                      const float* __restrict__ ln_b,
                      const float* __restrict__ thr_p,
                      const float* __restrict__ intr_p,
                      const float* __restrict__ steep_p,
                      const float* __restrict__ reset_p,
                      const float* __restrict__ W_cls,
                      const float* __restrict__ b_cls,
                      const _Float16* __restrict__ Bh_g,
                      const _Float16* __restrict__ Bl_g,
                      const _Float16* __restrict__ Wih_g,
                      const _Float16* __restrict__ Wil_g,
                      const _Float16* __restrict__ Wgh_g,
                      const _Float16* __restrict__ Wgl_g,
                      float* __restrict__ out)
{
    // Spikes in A-fragment layout, f16 hi/lo: idx = (k8*16 + m)*8 + (k&7)
    __shared__ _Float16 Ah[K8N * RPB * 8];   // 12 KB
    __shared__ _Float16 Al[K8N * RPB * 8];   // 12 KB
    __shared__ _Float16 xh[4 * RPB * 8];     // 1 KB  (x_t, K pad 32)
    __shared__ _Float16 xl[4 * RPB * 8];     // 1 KB
    __shared__ float red[6][RPB][2];
    __shared__ float musig[2][RPB];

    const int tid  = threadIdx.x;
    const int w    = tid >> 6;
    const int lane = tid & 63;
    const int quad = lane >> 4;
    const int l15  = lane & 15;
    const int row0 = blockIdx.x * RPB;

    // Per-column params for this thread's 4 n-values (n = w*64 + i*16 + l15)
    float gam[4], bet[4], thrv[4], intv[4], asp[4], rscv[4], binv[4], bgtv[4];
#pragma unroll
    for (int i = 0; i < 4; ++i) {
        int n_i = w * 64 + i * 16 + l15;
        bool a = n_i < NET;
        gam[i]  = a ? ln_g[n_i]   : 0.f;
        bet[i]  = a ? ln_b[n_i]   : 0.f;
        thrv[i] = a ? thr_p[n_i]  : 0.f;
        intv[i] = a ? intr_p[n_i] : 0.f;
        asp[i]  = a ? fabsf(steep_p[n_i]) : 0.f;
        rscv[i] = a ? reset_p[n_i] : 0.f;
        binv[i] = a ? b_in[n_i]   : 0.f;
        bgtv[i] = a ? b_gate[n_i] : 0.f;
    }

    float pot[4][4];
#pragma unroll
    for (int i = 0; i < 4; ++i)
#pragma unroll
        for (int r = 0; r < 4; ++r) pot[i][r] = 0.f;

    // Zero-init LDS spike/x buffers (initial spikes = 0; padding rows = 0)
    for (int e = tid; e < K8N * RPB * 8; e += NTHR) { Ah[e] = (_Float16)0.f; Al[e] = (_Float16)0.f; }
    for (int e = tid; e < 4 * RPB * 8; e += NTHR)   { xh[e] = (_Float16)0.f; xl[e] = (_Float16)0.f; }
    __syncthreads();
    // Stage x for t=0
    for (int e = tid; e < RPB * 28; e += NTHR) {
        int m = e / 28, f = e % 28;
        float v = x[((size_t)(row0 + m) * 64 + 0) * 28 + f];
        _Float16 h = (_Float16)v;
        int ix = ((f >> 3) * RPB + m) * 8 + (f & 7);
        xh[ix] = h; xl[ix] = (_Float16)(v - (float)h);
    }

    const int Ttot = 64 + *rsteps_p;

    const f16x8* Bph = (const f16x8*)Bh_g;
    const f16x8* Bpl = (const f16x8*)Bl_g;
    const f16x8* Aph = (const f16x8*)Ah;
    const f16x8* Apl = (const f16x8*)Al;
    const f16x8* Xph = (const f16x8*)xh;
    const f16x8* Xpl = (const f16x8*)xl;
    const int bb = quad * NPAD + w * 64 + l15;   // B-frag base (f16x8 units)
    const int ab = quad * RPB + l15;             // A-frag base (f16x8 units)

    for (int t = 0; t < Ttot; ++t) {
        __syncthreads();   // barrier A: spikes/x for step t visible

        f32x4 acc[4];
#pragma unroll
        for (int i = 0; i < 4; ++i) acc[i] = (f32x4){0.f, 0.f, 0.f, 0.f};

        // ---- Recurrent GEMM: acc[m][n] += sum_k spk[m][k] * W_rec[n][k] ----
        {
            f16x8 ch[4], cl[4], nh[4], nl[4];
#pragma unroll
            for (int i = 0; i < 4; ++i) { ch[i] = Bph[bb + i * 16]; cl[i] = Bpl[bb + i * 16]; }
#pragma unroll
            for (int kt = 0; kt < 12; ++kt) {
                if (kt < 11) {
#pragma unroll
                    for (int i = 0; i < 4; ++i) {
                        nh[i] = Bph[bb + (kt + 1) * (4 * NPAD) + i * 16];
                        nl[i] = Bpl[bb + (kt + 1) * (4 * NPAD) + i * 16];
                    }
                }
                f16x8 ah = Aph[ab + kt * 64];
                f16x8 al = Apl[ab + kt * 64];
#pragma unroll
                for (int i = 0; i < 4; ++i) {
                    acc[i] = __builtin_amdgcn_mfma_f32_16x16x32_f16(ah, ch[i], acc[i], 0, 0, 0);
                    acc[i] = __builtin_amdgcn_mfma_f32_16x16x32_f16(al, ch[i], acc[i], 0, 0, 0);
                    acc[i] = __builtin_amdgcn_mfma_f32_16x16x32_f16(ah, cl[i], acc[i], 0, 0, 0);
                }
                if (kt < 11) {
#pragma unroll
                    for (int i = 0; i < 4; ++i) { ch[i] = nh[i]; cl[i] = nl[i]; }
                }
            }
        }

        // ---- Gated input via MFMA (scan phase) ----
        if (t < 64) {
            f16x8 xa = Xph[ab];
            f16x8 xb = Xpl[ab];
#pragma unroll
            for (int i = 0; i < 4; ++i) {
                f16x8 ih = ((const f16x8*)Wih_g)[bb + i * 16];
                f16x8 il = ((const f16x8*)Wil_g)[bb + i * 16];
                f16x8 gh = ((const f16x8*)Wgh_g)[bb + i * 16];
                f16x8 gl = ((const f16x8*)Wgl_g)[bb + i * 16];
                f32x4 ia = (f32x4){binv[i], binv[i], binv[i], binv[i]};
                f32x4 ga = (f32x4){bgtv[i], bgtv[i], bgtv[i], bgtv[i]};
                ia = __builtin_amdgcn_mfma_f32_16x16x32_f16(xa, ih, ia, 0, 0, 0);
                ia = __builtin_amdgcn_mfma_f32_16x16x32_f16(xb, ih, ia, 0, 0, 0);
                ia = __builtin_amdgcn_mfma_f32_16x16x32_f16(xa, il, ia, 0, 0, 0);
                ga = __builtin_amdgcn_mfma_f32_16x16x32_f16(xa, gh, ga, 0, 0, 0);
                ga = __builtin_amdgcn_mfma_f32_16x16x32_f16(xb, gh, ga, 0, 0, 0);
                ga = __builtin_amdgcn_mfma_f32_16x16x32_f16(xa, gl, ga, 0, 0, 0);
#pragma unroll
                for (int r = 0; r < 4; ++r) acc[i][r] += ia[r] * sigm(ga[r]);
            }
        }

        // ---- LayerNorm stats: reduce over n (l15 lanes + waves) per row m ----
#pragma unroll
        for (int r = 0; r < 4; ++r) {
            float v  = acc[0][r] + acc[1][r] + acc[2][r] + acc[3][r];
            float v2 = acc[0][r] * acc[0][r] + acc[1][r] * acc[1][r]
                     + acc[2][r] * acc[2][r] + acc[3][r] * acc[3][r];
#pragma unroll
            for (int off = 1; off < 16; off <<= 1) {
                v  += __shfl_xor(v,  off);
                v2 += __shfl_xor(v2, off);
            }
            if (l15 == 0) { red[w][quad * 4 + r][0] = v; red[w][quad * 4 + r][1] = v2; }
        }
        __syncthreads();   // barrier B
        if (tid < RPB) {
            float s = 0.f, s2 = 0.f;
#pragma unroll
            for (int w2 = 0; w2 < 6; ++w2) { s += red[w2][tid][0]; s2 += red[w2][tid][1]; }
            float mu  = s * (1.f / NET);
            float var = s2 * (1.f / NET) - mu * mu;
            musig[0][tid] = mu;
            musig[1][tid] = rsqrtf(var + 1e-5f);
        }
        __syncthreads();   // barrier C

        float mu_r[4], rs_r[4];
#pragma unroll
        for (int r = 0; r < 4; ++r) { mu_r[r] = musig[0][quad * 4 + r]; rs_r[r] = musig[1][quad * 4 + r]; }

        // ---- LN apply + PulseTGAU neuron, write split spikes to A-layout ----
#pragma unroll
        for (int i = 0; i < 4; ++i) {
            int n_i  = w * 64 + i * 16 + l15;
            int base = ((n_i >> 3) * RPB) * 8 + (n_i & 7);
#pragma unroll
            for (int r = 0; r < 4; ++r) {
                int m = quad * 4 + r;
                float cur = (acc[i][r] - mu_r[r]) * rs_r[r] * gam[i] + bet[i];
                float p   = pot[i][r] * 0.95f + cur + intv[i];
                float gp  = p - thrv[i];
                float sg  = sigm(gp * asp[i]);
                float sp  = sigm(gp);
                float o   = gp * sp * sg;
                pot[i][r] = p - rscv[i] * (gp * sg);
                _Float16 h = (_Float16)o;
                Ah[base + m * 8] = h;
                Al[base + m * 8] = (_Float16)(o - (float)h);
            }
        }

        // Stage x for t+1 (safe: reads of xh/xl for step t finished before barrier B)
        if (t < 63) {
            for (int e = tid; e < RPB * 28; e += NTHR) {
                int m = e / 28, f = e % 28;
                float v = x[((size_t)(row0 + m) * 64 + (t + 1)) * 28 + f];
                _Float16 h = (_Float16)v;
                int ix = ((f >> 3) * RPB + m) * 8 + (f & 7);
                xh[ix] = h; xl[ix] = (_Float16)(v - (float)h);
            }
        }
    }

    __syncthreads();
    // ---- Classifier epilogue ----
    if (tid < RPB * 10) {
        int r = tid / 10, c = tid - r * 10;
        const float* wc = W_cls + c * NET;
        float s = b_cls[c];
        for (int k = 0; k < NET; ++k) {
            int ix = ((k >> 3) * RPB + r) * 8 + (k & 7);
            float sv = (float)Ah[ix] + (float)Al[ix];
            s = fmaf(sv, wc[k], s);
        }
        out[(size_t)(row0 + r) * 10 + c] = s;
    }
}

extern "C" void kernel_launch(void* const* d_in, const int* in_sizes, int n_in,
                              void* d_out, int out_size, void* d_ws, size_t ws_size,
                              hipStream_t stream)
{
    const float* x      = (const float*)d_in[0];
    const int*   rsteps = (const int*)  d_in[1];
    const float* W_in   = (const float*)d_in[2];
    const float* b_in   = (const float*)d_in[3];
    const float* W_gate = (const float*)d_in[4];
    const float* b_gate = (const float*)d_in[5];
    const float* W_rec  = (const float*)d_in[6];
    const float* ln_g   = (const float*)d_in[7];
    const float* ln_b   = (const float*)d_in[8];
    const float* thr    = (const float*)d_in[9];
    const float* intr   = (const float*)d_in[10];
    const float* steep  = (const float*)d_in[11];
    const float* rsc    = (const float*)d_in[12];
    const float* W_cls  = (const float*)d_in[13];
    const float* b_cls  = (const float*)d_in[14];
    float*       out    = (float*)d_out;

    _Float16* Bh  = (_Float16*)d_ws;
    _Float16* Bl  = Bh  + WREC_E;
    _Float16* Wih = Bl  + WREC_E;
    _Float16* Wil = Wih + WIN_E;
    _Float16* Wgh = Wil + WIN_E;
    _Float16* Wgl = Wgh + WIN_E;

    const int total = WREC_E + 2 * WIN_E;
    prep_kernel<<<dim3((total + 255) / 256), dim3(256), 0, stream>>>(
        W_rec, W_in, W_gate, Bh, Bl, Wih, Wil, Wgh, Wgl);
    resonator_kernel<<<dim3(NBLK), dim3(NTHR), 0, stream>>>(
        x, rsteps, b_in, b_gate, ln_g, ln_b, thr, intr, steep, rsc,
        W_cls, b_cls, Bh, Bl, Wih, Wil, Wgh, Wgl, out);
}

// Round 3
// 767.060 us; speedup vs baseline: 5.6204x; 3.1753x over previous
//
#include <hip/hip_runtime.h>
#include <math.h>

// EmergentResonator — MFMA split-f16, R3.
// 256 blocks x 16 rows, 512 threads (8 waves x 3 n-tiles). Per step:
// [16x384]x[384x384] GEMM via mfma_f32_16x16x32_f16, 2-way f16 split (3 products).
// R2 lesson: explicit double-buffer regs at VGPR_Count=128 caused ~4.8 GB of
// scratch spill traffic (FETCH_SIZE matched spill arithmetic). R3: kt-outer/i-inner
// loop with unroll-4 window, 8-wave balance, input weights staged in LDS.

#define NET    360
#define NPAD   384
#define K8N    48          // NPAD/8 k8-groups for W_rec
#define RPB    16
#define NBLK   256
#define NTHR   512         // 8 waves; wave w owns n-tiles 3w..3w+2
#define NTILE  3

typedef _Float16 f16x8 __attribute__((ext_vector_type(8)));
typedef float    f32x4 __attribute__((ext_vector_type(4)));

#define WREC_E (K8N * NPAD * 8)    // 147456 f16 per term
#define WIN_E  (4 * NPAD * 8)      // 12288 f16 per term (K pad 32)

// Split fp32 weights into f16 hi/lo in MFMA B-fragment layout:
// idx = (k8*NPAD + n)*8 + (k&7), B[k][n] = W[n*K + k], zero-padded.
__global__ void prep_kernel(const float* __restrict__ W_rec,
                            const float* __restrict__ W_in,
                            const float* __restrict__ W_gate,
                            _Float16* __restrict__ Bh, _Float16* __restrict__ Bl,
                            _Float16* __restrict__ Wio)
{
    int idx = blockIdx.x * 256 + threadIdx.x;
    if (idx < WREC_E) {
        int k8 = idx / (NPAD * 8), rem = idx % (NPAD * 8);
        int n = rem >> 3, j = rem & 7, k = k8 * 8 + j;
        float v = (k < NET && n < NET) ? W_rec[n * NET + k] : 0.f;
        _Float16 h = (_Float16)v;
        Bh[idx] = h; Bl[idx] = (_Float16)(v - (float)h);
    } else if (idx < WREC_E + 2 * WIN_E) {
        // Wio layout: [0]=Wih, [1]=Wil, [2]=Wgh, [3]=Wgl, each WIN_E f16.
        int e = idx - WREC_E;                 // 0 .. 2*WIN_E-1
        int which = e / WIN_E;                // 0 = W_in, 1 = W_gate
        int f = e % WIN_E;
        int k8 = f / (NPAD * 8), rem = f % (NPAD * 8);
        int n = rem >> 3, j = rem & 7, k = k8 * 8 + j;
        const float* W = which ? W_gate : W_in;
        float v = (k < 28 && n < NET) ? W[n * 28 + k] : 0.f;
        _Float16 h = (_Float16)v;
        Wio[(2 * which) * WIN_E + f]     = h;
        Wio[(2 * which + 1) * WIN_E + f] = (_Float16)(v - (float)h);
    }
}

__device__ __forceinline__ float sigm(float v) { return 1.f / (1.f + __expf(-v)); }

__global__ __launch_bounds__(NTHR, 2)
void resonator_kernel(const float* __restrict__ x,
                      const int*   __restrict__ rsteps_p,
                      const float* __restrict__ b_in,
                      const float* __restrict__ b_gate,
                      const float* __restrict__ ln_g,
                      const float* __restrict__ ln_b,
                      const float* __restrict__ thr_p,
                      const float* __restrict__ intr_p,
                      const float* __restrict__ steep_p,
                      const float* __restrict__ reset_p,
                      const float* __restrict__ W_cls,
                      const float* __restrict__ b_cls,
                      const _Float16* __restrict__ Bh_g,
                      const _Float16* __restrict__ Bl_g,
                      const _Float16* __restrict__ Wio_g,
                      float* __restrict__ out)
{
    // Spikes in A-fragment layout, f16 hi/lo: idx = (k8*16 + m)*8 + (k&7)
    __shared__ __align__(16) _Float16 Ah[K8N * RPB * 8];   // 12 KB
    __shared__ __align__(16) _Float16 Al[K8N * RPB * 8];   // 12 KB
    __shared__ __align__(16) _Float16 xh[4 * RPB * 8];     // 1 KB  (x_t, K pad 32)
    __shared__ __align__(16) _Float16 xl[4 * RPB * 8];     // 1 KB
    __shared__ __align__(16) _Float16 Wio[4 * WIN_E];      // 96 KB: Wih,Wil,Wgh,Wgl
    __shared__ float red[8][RPB][2];
    __shared__ float musig[2][RPB];

    const int tid  = threadIdx.x;
    const int w    = tid >> 6;
    const int lane = tid & 63;
    const int quad = lane >> 4;
    const int l15  = lane & 15;
    const int row0 = blockIdx.x * RPB;

    // Per-column params for this thread's NTILE n-values (n = (w*3+i)*16 + l15)
    float gam[NTILE], bet[NTILE], thrv[NTILE], intv[NTILE], asp[NTILE], rscv[NTILE],
          binv[NTILE], bgtv[NTILE];
#pragma unroll
    for (int i = 0; i < NTILE; ++i) {
        int n_i = (w * NTILE + i) * 16 + l15;
        bool a = n_i < NET;
        gam[i]  = a ? ln_g[n_i]   : 0.f;
        bet[i]  = a ? ln_b[n_i]   : 0.f;
        thrv[i] = a ? thr_p[n_i]  : 0.f;
        intv[i] = a ? intr_p[n_i] : 0.f;
        asp[i]  = a ? fabsf(steep_p[n_i]) : 0.f;
        rscv[i] = a ? reset_p[n_i] : 0.f;
        binv[i] = a ? b_in[n_i]   : 0.f;
        bgtv[i] = a ? b_gate[n_i] : 0.f;
    }

    float pot[NTILE][4];
#pragma unroll
    for (int i = 0; i < NTILE; ++i)
#pragma unroll
        for (int r = 0; r < 4; ++r) pot[i][r] = 0.f;

    // Zero-init spike/x LDS; stage input-weight LDS from global (uint4 copies).
    for (int e = tid; e < K8N * RPB * 8; e += NTHR) { Ah[e] = (_Float16)0.f; Al[e] = (_Float16)0.f; }
    for (int e = tid; e < 4 * RPB * 8; e += NTHR)   { xh[e] = (_Float16)0.f; xl[e] = (_Float16)0.f; }
    {
        const uint4* src = (const uint4*)Wio_g;
        uint4* dst = (uint4*)Wio;
        for (int e = tid; e < (4 * WIN_E) / 8; e += NTHR) dst[e] = src[e];
    }
    __syncthreads();
    // Stage x for t=0
    for (int e = tid; e < RPB * 28; e += NTHR) {
        int m = e / 28, f = e % 28;
        float v = x[((size_t)(row0 + m) * 64 + 0) * 28 + f];
        _Float16 h = (_Float16)v;
        int ix = ((f >> 3) * RPB + m) * 8 + (f & 7);
        xh[ix] = h; xl[ix] = (_Float16)(v - (float)h);
    }

    const int Ttot = 64 + *rsteps_p;

    const f16x8* Bph = (const f16x8*)Bh_g;
    const f16x8* Bpl = (const f16x8*)Bl_g;
    const f16x8* Aph = (const f16x8*)Ah;
    const f16x8* Apl = (const f16x8*)Al;
    const f16x8* Xph = (const f16x8*)xh;
    const f16x8* Xpl = (const f16x8*)xl;
    const f16x8* Wp  = (const f16x8*)Wio;
    const int bb = quad * NPAD + w * (NTILE * 16) + l15;  // B-frag base (f16x8 units)
    const int ab = quad * RPB + l15;                      // A-frag base (f16x8 units)

    for (int t = 0; t < Ttot; ++t) {
        __syncthreads();   // barrier A: spikes/x for step t visible

        f32x4 acc[NTILE];
#pragma unroll
        for (int i = 0; i < NTILE; ++i) acc[i] = (f32x4){0.f, 0.f, 0.f, 0.f};

        // ---- Recurrent GEMM: acc[m][n] += sum_k spk[m][k] * W_rec[n][k] ----
#pragma unroll 4
        for (int kt = 0; kt < 12; ++kt) {
            f16x8 ah = Aph[ab + kt * 64];
            f16x8 al = Apl[ab + kt * 64];
#pragma unroll
            for (int i = 0; i < NTILE; ++i) {
                f16x8 bh = Bph[bb + i * 16 + kt * (4 * NPAD)];
                f16x8 bl = Bpl[bb + i * 16 + kt * (4 * NPAD)];
                acc[i] = __builtin_amdgcn_mfma_f32_16x16x32_f16(ah, bh, acc[i], 0, 0, 0);
                acc[i] = __builtin_amdgcn_mfma_f32_16x16x32_f16(al, bh, acc[i], 0, 0, 0);
                acc[i] = __builtin_amdgcn_mfma_f32_16x16x32_f16(ah, bl, acc[i], 0, 0, 0);
            }
        }

        // ---- Gated input via MFMA from LDS weights (scan phase) ----
        if (t < 64) {
            f16x8 xa = Xph[ab];
            f16x8 xb = Xpl[ab];
#pragma unroll
            for (int i = 0; i < NTILE; ++i) {
                f16x8 ih = Wp[0 * (WIN_E / 8) + bb + i * 16];
                f16x8 il = Wp[1 * (WIN_E / 8) + bb + i * 16];
                f16x8 gh = Wp[2 * (WIN_E / 8) + bb + i * 16];
                f16x8 gl = Wp[3 * (WIN_E / 8) + bb + i * 16];
                f32x4 ia = (f32x4){binv[i], binv[i], binv[i], binv[i]};
                f32x4 ga = (f32x4){bgtv[i], bgtv[i], bgtv[i], bgtv[i]};
                ia = __builtin_amdgcn_mfma_f32_16x16x32_f16(xa, ih, ia, 0, 0, 0);
                ia = __builtin_amdgcn_mfma_f32_16x16x32_f16(xb, ih, ia, 0, 0, 0);
                ia = __builtin_amdgcn_mfma_f32_16x16x32_f16(xa, il, ia, 0, 0, 0);
                ga = __builtin_amdgcn_mfma_f32_16x16x32_f16(xa, gh, ga, 0, 0, 0);
                ga = __builtin_amdgcn_mfma_f32_16x16x32_f16(xb, gh, ga, 0, 0, 0);
                ga = __builtin_amdgcn_mfma_f32_16x16x32_f16(xa, gl, ga, 0, 0, 0);
#pragma unroll
                for (int r = 0; r < 4; ++r) acc[i][r] += ia[r] * sigm(ga[r]);
            }
        }

        // ---- LayerNorm stats: reduce over n (16 l15-lanes, then 8 waves) ----
#pragma unroll
        for (int r = 0; r < 4; ++r) {
            float v = 0.f, v2 = 0.f;
#pragma unroll
            for (int i = 0; i < NTILE; ++i) { v += acc[i][r]; v2 += acc[i][r] * acc[i][r]; }
#pragma unroll
            for (int off = 1; off < 16; off <<= 1) {
                v  += __shfl_xor(v,  off);
                v2 += __shfl_xor(v2, off);
            }
            if (l15 == 0) { red[w][quad * 4 + r][0] = v; red[w][quad * 4 + r][1] = v2; }
        }
        __syncthreads();   // barrier B
        if (tid < RPB) {
            float s = 0.f, s2 = 0.f;
#pragma unroll
            for (int w2 = 0; w2 < 8; ++w2) { s += red[w2][tid][0]; s2 += red[w2][tid][1]; }
            float mu  = s * (1.f / NET);
            float var = s2 * (1.f / NET) - mu * mu;
            musig[0][tid] = mu;
            musig[1][tid] = rsqrtf(var + 1e-5f);
        }
        __syncthreads();   // barrier C

        float mu_r[4], rs_r[4];
#pragma unroll
        for (int r = 0; r < 4; ++r) { mu_r[r] = musig[0][quad * 4 + r]; rs_r[r] = musig[1][quad * 4 + r]; }

        // ---- LN apply + PulseTGAU neuron, write split spikes to A-layout ----
#pragma unroll
        for (int i = 0; i < NTILE; ++i) {
            int n_i  = (w * NTILE + i) * 16 + l15;
            int base = ((n_i >> 3) * RPB) * 8 + (n_i & 7);
#pragma unroll
            for (int r = 0; r < 4; ++r) {
                int m = quad * 4 + r;
                float cur = (acc[i][r] - mu_r[r]) * rs_r[r] * gam[i] + bet[i];
                float p   = pot[i][r] * 0.95f + cur + intv[i];
                float gp  = p - thrv[i];
                float sg  = sigm(gp * asp[i]);
                float sp  = sigm(gp);
                float o   = gp * sp * sg;
                pot[i][r] = p - rscv[i] * (gp * sg);
                _Float16 h = (_Float16)o;
                Ah[base + m * 8] = h;
                Al[base + m * 8] = (_Float16)(o - (float)h);
            }
        }

        // Stage x for t+1 (xh reads for step t all happened before barrier B)
        if (t < 63) {
            for (int e = tid; e < RPB * 28; e += NTHR) {
                int m = e / 28, f = e % 28;
                float v = x[((size_t)(row0 + m) * 64 + (t + 1)) * 28 + f];
                _Float16 h = (_Float16)v;
                int ix = ((f >> 3) * RPB + m) * 8 + (f & 7);
                xh[ix] = h; xl[ix] = (_Float16)(v - (float)h);
            }
        }
    }

    __syncthreads();
    // ---- Classifier epilogue ----
    if (tid < RPB * 10) {
        int r = tid / 10, c = tid - r * 10;
        const float* wc = W_cls + c * NET;
        float s = b_cls[c];
        for (int k = 0; k < NET; ++k) {
            int ix = ((k >> 3) * RPB + r) * 8 + (k & 7);
            float sv = (float)Ah[ix] + (float)Al[ix];
            s = fmaf(sv, wc[k], s);
        }
        out[(size_t)(row0 + r) * 10 + c] = s;
    }
}

extern "C" void kernel_launch(void* const* d_in, const int* in_sizes, int n_in,
                              void* d_out, int out_size, void* d_ws, size_t ws_size,
                              hipStream_t stream)
{
    const float* x      = (const float*)d_in[0];
    const int*   rsteps = (const int*)  d_in[1];
    const float* W_in   = (const float*)d_in[2];
    const float* b_in   = (const float*)d_in[3];
    const float* W_gate = (const float*)d_in[4];
    const float* b_gate = (const float*)d_in[5];
    const float* W_rec  = (const float*)d_in[6];
    const float* ln_g   = (const float*)d_in[7];
    const float* ln_b   = (const float*)d_in[8];
    const float* thr    = (const float*)d_in[9];
    const float* intr   = (const float*)d_in[10];
    const float* steep  = (const float*)d_in[11];
    const float* rsc    = (const float*)d_in[12];
    const float* W_cls  = (const float*)d_in[13];
    const float* b_cls  = (const float*)d_in[14];
    float*       out    = (float*)d_out;

    _Float16* Bh  = (_Float16*)d_ws;
    _Float16* Bl  = Bh + WREC_E;
    _Float16* Wio = Bl + WREC_E;     // 4*WIN_E: Wih, Wil, Wgh, Wgl

    const int total = WREC_E + 2 * WIN_E;
    prep_kernel<<<dim3((total + 255) / 256), dim3(256), 0, stream>>>(
        W_rec, W_in, W_gate, Bh, Bl, Wio);
    resonator_kernel<<<dim3(NBLK), dim3(NTHR), 0, stream>>>(
        x, rsteps, b_in, b_gate, ln_g, ln_b, thr, intr, steep, rsc,
        W_cls, b_cls, Bh, Bl, Wio, out);
}